// Round 13
// baseline (5510.254 us; speedup 1.0000x reference)
//
// Chunked parallel linear-RNN scan for MI355X (gfx950).
//   projS[t] = x[:,t-1] @ w_ih^T + b_ih  (TIME-SHIFTED projection)
//   h_t  = h_{t-1} @ w_hh^T + projS[t]   (chunked scan)
// R13: k_scan2 re-tiled to 32-row blocks (512 blocks, 8 waves, 64KB LDS) so
// TWO blocks co-reside per CU -- block A's memory-bound sweep overlaps block
// B's MFMA phase (CU-level TLP; in-wave pipelining is impossible at the hard
// 128 reg/wave cap). Values bit-identical to R12. R12 core: shifted-proj
// in-place out2, single fp16 W plane (L2-resident), KS boundary scan.

#include <hip/hip_runtime.h>
#include <stdint.h>

typedef unsigned int u32;
typedef unsigned short u16;
typedef _Float16 f16;
typedef __attribute__((ext_vector_type(4))) float f32x4;
typedef __attribute__((ext_vector_type(8))) short s16x8;
typedef __attribute__((ext_vector_type(8))) _Float16 f16x8;

#define NB 128
#define TS 2048
#define ID 128
#define HD 1024
#define LCH 16
#define CCH 128
#define NJT 64  // HD/16

__device__ __forceinline__ u16 f2bf(float f) {
  u32 u = __builtin_bit_cast(u32, f);
  u += 0x7FFFu + ((u >> 16) & 1u);
  return (u16)(u >> 16);
}
__device__ __forceinline__ float bf2f(u16 h) {
  u32 u = ((u32)h) << 16;
  return __builtin_bit_cast(float, u);
}
__device__ __forceinline__ void split2(float f, u16& hi, u16& lo) {
  hi = f2bf(f);
  lo = f2bf(f - bf2f(hi));
}
__device__ __forceinline__ float ntl(const float* p) { return __builtin_nontemporal_load(p); }
__device__ __forceinline__ f32x4 ntl4(const float* p) {
  return __builtin_nontemporal_load((const f32x4*)p);
}
__device__ __forceinline__ void nts(float v, float* p) { __builtin_nontemporal_store(v, p); }
__device__ __forceinline__ void nts4(f32x4 v, float* p) {
  __builtin_nontemporal_store(v, (f32x4*)p);
}
#define MFMA16(a, b, c) __builtin_amdgcn_mfma_f32_16x16x32_bf16((a), (b), (c), 0, 0, 0)
#define MFMAH(a, b, c) __builtin_amdgcn_mfma_f32_16x16x32_f16((a), (b), (c), 0, 0, 0)

// ---------------- prep kernels ----------------

// Pack B[k][j] = src[k*sk + j*sj] into MFMA-fragment order (bf16 hi/lo).
__global__ void k_pack_b(const float* __restrict__ src, long sk, long sj, int jtiles,
                         int total, u16* __restrict__ dh, u16* __restrict__ dl) {
  const int fid = blockIdx.x * blockDim.x + threadIdx.x;
  if (fid >= total) return;
  const int lane = fid & 63;
  const int tt = fid >> 6;
  const int jt = tt % jtiles;
  const int kt = tt / jtiles;
  const int k0 = kt * 32 + (lane >> 4) * 8;
  const long j = jt * 16 + (lane & 15);
  s16x8 hv, lv;
#pragma unroll
  for (int i = 0; i < 8; ++i) {
    const float v = src[(long)(k0 + i) * sk + j * sj];
    u16 hh, ll; split2(v, hh, ll);
    hv[i] = (short)hh; lv[i] = (short)ll;
  }
  *(s16x8*)(dh + (long)fid * 8) = hv;
  *(s16x8*)(dl + (long)fid * 8) = lv;
}

// Pack single-fp16 plane (round-to-nearest fp16 of W).
__global__ void k_pack_f16(const float* __restrict__ src, long sk, long sj, int jtiles,
                           int total, u16* __restrict__ dh) {
  const int fid = blockIdx.x * blockDim.x + threadIdx.x;
  if (fid >= total) return;
  const int lane = fid & 63;
  const int tt = fid >> 6;
  const int jt = tt % jtiles;
  const int kt = tt / jtiles;
  const int k0 = kt * 32 + (lane >> 4) * 8;
  const long j = jt * 16 + (lane & 15);
  s16x8 hv;
#pragma unroll
  for (int i = 0; i < 8; ++i) {
    const float v = src[(long)(k0 + i) * sk + j * sj];
    const f16 hh = (f16)v;
    hv[i] = (short)__builtin_bit_cast(u16, hh);
  }
  *(s16x8*)(dh + (long)fid * 8) = hv;
}

// Split to row-major bf16 hi/lo planes.
__global__ void k_split_strided(const float* __restrict__ src, long sk, long sj, int nj,
                                long total, u16* __restrict__ dh, u16* __restrict__ dl) {
  const long i = (long)blockIdx.x * blockDim.x + threadIdx.x;
  if (i >= total) return;
  const long k = i / nj;
  const long j = i % nj;
  u16 hh, ll;
  split2(src[k * sk + j * sj], hh, ll);
  dh[i] = hh;
  dl[i] = ll;
}

// ---------------- generic bf16x3 GEMM ----------------
// C[m,n] = sum_k A[m,k]*B[k,n]. Block (32*RT)x(32*CT), 4 waves 2x2.
// ASRC 0: A from pre-split rm planes. 1: A from fp32 (split on the fly).
// EPI 1: +bias(aux), LDS-coalesced NT store to cout, TIME-SHIFTED:
//        row (n,t) stored at projS slot t+1 (t<TS-1); t==0 also at slot 0.
// EPI 2: Z-init: z = v + projS-gather(aux); zb16 <- bf16(z); atomicMax per
//        chunk into zmx.
// EPI 3: write rm bf16 hi/lo planes AND packed bf16 hi/lo planes.
// EPI 4: fused Kogge-Stone round (ksd = d): blocks with blockIdx.x < d copy
//        ein tile -> drm tile; else out[C] = A[C-d]*B + ein[C] (split planes).
template <int EPI, int RT, int CT, int ASRC>
__global__ __launch_bounds__(256) void k_gemm3(
    const u16* __restrict__ ahi, const u16* __restrict__ alo,
    const float* __restrict__ af32, long lda,
    const u16* __restrict__ bhi, const u16* __restrict__ blo, int ksteps,
    const float* __restrict__ aux, float* __restrict__ cout, long ldc,
    u16* __restrict__ drm_h, u16* __restrict__ drm_l,
    u16* __restrict__ dpk_h, u16* __restrict__ dpk_l,
    u16* __restrict__ zb16, u32* __restrict__ zmx,
    const u16* __restrict__ einh, const u16* __restrict__ einl, int ksd) {
  __shared__ float cb[4][16][33];
  const int tid = threadIdx.x;
  const int l = tid & 63;
  const int w = tid >> 6;
  const int wr = w >> 1, wc = w & 1;
  const int n0 = blockIdx.y * (32 * CT) + wc * (16 * CT);
  if constexpr (EPI == 4) {
    if ((int)blockIdx.x < ksd) {
      // pass-through: copy ein tile -> drm tile
      const long rbase = (long)blockIdx.x * (32 * RT);
      const int ncols8 = (32 * CT) / 8;
      const int nb0 = blockIdx.y * (32 * CT);
      for (int i = tid; i < (32 * RT) * ncols8; i += 256) {
        const int rr = i / ncols8;
        const int cc = (i % ncols8) * 8;
        const long o = (rbase + rr) * HD + nb0 + cc;
        *(s16x8*)(drm_h + o) = *(const s16x8*)(einh + o);
        *(s16x8*)(drm_l + o) = *(const s16x8*)(einl + o);
      }
      return;
    }
  }
  const long m0 = ((long)blockIdx.x - ((EPI == 4) ? ksd : 0)) * (32 * RT) + wr * (16 * RT);
  const int arow = l & 15, koff = (l >> 4) * 8;
  f32x4 acc[RT][CT];
#pragma unroll
  for (int a = 0; a < RT; ++a)
#pragma unroll
    for (int b = 0; b < CT; ++b) acc[a][b] = (f32x4){0.f, 0.f, 0.f, 0.f};
#pragma unroll 1
  for (int ks = 0; ks < ksteps; ++ks) {
    s16x8 AH[RT], AL[RT], BH[CT], BL[CT];
#pragma unroll
    for (int rt = 0; rt < RT; ++rt) {
      const long off = (m0 + rt * 16 + arow) * lda + ks * 32 + koff;
      if constexpr (ASRC == 0) {
        AH[rt] = *(const s16x8*)(ahi + off);
        AL[rt] = *(const s16x8*)(alo + off);
      } else {
        const float4 f0 = *(const float4*)(af32 + off);
        const float4 f1 = *(const float4*)(af32 + off + 4);
        float fv[8] = {f0.x, f0.y, f0.z, f0.w, f1.x, f1.y, f1.z, f1.w};
        s16x8 hv, lv;
#pragma unroll
        for (int i = 0; i < 8; ++i) {
          u16 hh, ll; split2(fv[i], hh, ll);
          hv[i] = (short)hh; lv[i] = (short)ll;
        }
        AH[rt] = hv; AL[rt] = lv;
      }
    }
#pragma unroll
    for (int ct = 0; ct < CT; ++ct) {
      const long off = (((long)ks * NJT + (n0 >> 4) + ct) * 64 + l) * 8;
      BH[ct] = *(const s16x8*)(bhi + off);
      BL[ct] = *(const s16x8*)(blo + off);
    }
#pragma unroll
    for (int ct = 0; ct < CT; ++ct)
#pragma unroll
      for (int rt = 0; rt < RT; ++rt) {
        acc[rt][ct] = MFMA16(AH[rt], BH[ct], acc[rt][ct]);
        acc[rt][ct] = MFMA16(AL[rt], BH[ct], acc[rt][ct]);
        acc[rt][ct] = MFMA16(AH[rt], BL[ct], acc[rt][ct]);
      }
  }
  const int crow = (l >> 4) * 4, ccol = l & 15;
  if constexpr (EPI == 1) {
#pragma unroll
    for (int rt = 0; rt < RT; ++rt)
#pragma unroll
      for (int ctp = 0; ctp < CT / 2; ++ctp) {
#pragma unroll
        for (int e = 0; e < 2; ++e)
#pragma unroll
          for (int r = 0; r < 4; ++r)
            cb[w][crow + r][e * 16 + ccol] = acc[rt][2 * ctp + e][r];
        const int rr = l >> 2, c8 = (l & 3) * 8;
        const int colg = n0 + ctp * 32 + c8;
        const float4 b0 = *(const float4*)&aux[colg];
        const float4 b1 = *(const float4*)&aux[colg + 4];
        f32x4 v0, v1;
        v0[0] = cb[w][rr][c8 + 0] + b0.x; v0[1] = cb[w][rr][c8 + 1] + b0.y;
        v0[2] = cb[w][rr][c8 + 2] + b0.z; v0[3] = cb[w][rr][c8 + 3] + b0.w;
        v1[0] = cb[w][rr][c8 + 4] + b1.x; v1[1] = cb[w][rr][c8 + 5] + b1.y;
        v1[2] = cb[w][rr][c8 + 6] + b1.z; v1[3] = cb[w][rr][c8 + 7] + b1.w;
        const long row = m0 + rt * 16 + rr;
        const int t = (int)(row & (TS - 1));
        if (t != TS - 1) {
          nts4(v0, cout + (row + 1) * ldc + colg);
          nts4(v1, cout + (row + 1) * ldc + colg + 4);
        }
        if (t == 0) {
          nts4(v0, cout + row * ldc + colg);
          nts4(v1, cout + row * ldc + colg + 4);
        }
      }
  } else if constexpr (EPI == 2) {
    float mym = 0.f;
#pragma unroll
    for (int rt = 0; rt < RT; ++rt)
#pragma unroll
      for (int ct = 0; ct < CT; ++ct) {
        const int col = n0 + ct * 16 + ccol;
#pragma unroll
        for (int r = 0; r < 4; ++r) {
          const long row = m0 + rt * 16 + crow + r;
          const int slot = (int)(row >> 7);      // chunk c-1
          const int n = (int)(row & 127);
          const float z = acc[rt][ct][r] +
              aux[((long)n * TS + (long)(slot + 1) * LCH) * HD + col];
          zb16[((long)slot * NB + n) * HD + col] = f2bf(z);
          mym = fmaxf(mym, fabsf(z));
        }
      }
#pragma unroll
    for (int d = 1; d < 64; d <<= 1) mym = fmaxf(mym, __shfl_xor(mym, d));
    if (l == 0) {
      const int slot = (int)(m0 >> 7);
      atomicMax(&zmx[slot + 1], __builtin_bit_cast(u32, mym));
    }
  } else if constexpr (EPI == 4) {
    const long rshift = (long)ksd * (32 * RT);
#pragma unroll
    for (int rt = 0; rt < RT; ++rt)
#pragma unroll
      for (int ct = 0; ct < CT; ++ct) {
        const int col = n0 + ct * 16 + ccol;
#pragma unroll
        for (int r = 0; r < 4; ++r) {
          const long row = m0 + rt * 16 + crow + r;
          const long o = (row + rshift) * HD + col;
          const float v = acc[rt][ct][r] + bf2f(einh[o]) + bf2f(einl[o]);
          u16 hh, ll; split2(v, hh, ll);
          drm_h[o] = hh;
          drm_l[o] = ll;
        }
      }
  } else {
#pragma unroll
    for (int rt = 0; rt < RT; ++rt)
#pragma unroll
      for (int ct = 0; ct < CT; ++ct) {
        const int col = n0 + ct * 16 + ccol;
#pragma unroll
        for (int r = 0; r < 4; ++r) {
          const long row = m0 + rt * 16 + crow + r;
          const float v = acc[rt][ct][r];
          u16 hh, ll; split2(v, hh, ll);
          drm_h[row * HD + col] = hh;
          drm_l[row * HD + col] = ll;
          const int lane2 = ((((int)row >> 3) & 3) << 4) | (col & 15);
          const long poff = (((row >> 5) * NJT + (col >> 4)) * 64 + lane2) * 8 + (row & 7);
          dpk_h[poff] = hh;
          dpk_l[poff] = ll;
        }
      }
  }
}

// ---------------- phases B / D: per-chunk fp16 scan ----------------
// 512 blocks = 128 chunks x 4 row-groups of 32; 8 waves (2/SIMD) -- TWO
// blocks co-resident per CU (64KB LDS each): one block's memory-bound sweep
// overlaps the other's MFMA phase.
// State: fp16 plane [32][1024] in LDS, r&15 swizzle. W: single fp16 pack
// (2MB, L2-resident; co-resident blocks share the stream).
// Step = { MFMA } -> bar -> { writeback plane } -> bar -> { sweep: v = plane
// + projS[t]*inv_s; EMIT: out1[t], out2[t] <- v*s (out2 in-place over projS,
// dataflow-ordered) } -> bar.
template <int EMIT>
__global__ __launch_bounds__(512, 4) __attribute__((amdgpu_waves_per_eu(4, 4)))
void k_scan2(
    const float* __restrict__ projS, const float* __restrict__ initial,
    const u16* __restrict__ wph,
    const u16* __restrict__ zbuf, const u32* __restrict__ zmx,
    u16* __restrict__ ebh, u16* __restrict__ ebl,
    float* __restrict__ out1, float* __restrict__ out2) {
  __shared__ u16 st[32 * HD];
  const int b = blockIdx.x;
  const int c = b >> 2;
  const int g = b & 3;
  const int tid = threadIdx.x;
  const int l = tid & 63;
  const int w = tid >> 6;  // 0..7
  const long t0 = (long)c * LCH;
  const int ccol = l & 15;
  const int q = l >> 4;
  const int jt0 = w * 8;   // 8 col-tiles (128 cols) per wave
  const int akey = l & 15;

  float s = 1.f, inv_s = 1.f;
  if constexpr (EMIT) {
    const u32 zb = zmx[c];
    const int ex = (int)((zb >> 23) & 255u) - 127;
    const int k = ex > 8 ? ex - 8 : 0;
    s = __builtin_bit_cast(float, (u32)(127 + k) << 23);
    inv_s = __builtin_bit_cast(float, (u32)(127 - k) << 23);
  }

  // Init state plane (+ for EMIT, emit out[t0]).
  for (int i = tid; i < 32 * HD; i += 512) {
    const int r = i >> 10;
    const int col = i & (HD - 1);
    const int n = g * 32 + r;
    float v;
    if (c == 0) {
      v = ntl(initial + (long)n * HD + col) + ntl(projS + ((long)n * TS) * HD + col);
    } else {
      if constexpr (EMIT) v = bf2f(zbuf[((long)(c - 1) * NB + n) * HD + col]);
      else                v = ntl(projS + ((long)n * TS + t0) * HD + col);
    }
    const f16 hv = (f16)(v * inv_s);
    const int si = r * HD + ((((col >> 3) ^ (r & 15)) << 3) | (col & 7));
    st[si] = __builtin_bit_cast(u16, hv);
    if constexpr (EMIT) {
      const long o = ((long)n * TS + t0) * HD + col;
      nts(v, out1 + o);
      nts(v, out2 + o);
    }
  }
  __syncthreads();

#pragma unroll 1
  for (int step = 1; step < LCH; ++step) {
    const long t = t0 + step;
    f32x4 acc[2][8];
#pragma unroll
    for (int rt = 0; rt < 2; ++rt)
#pragma unroll
      for (int ct = 0; ct < 8; ++ct) acc[rt][ct] = (f32x4){0.f, 0.f, 0.f, 0.f};
    __builtin_amdgcn_s_setprio(1);
#pragma unroll 2
    for (int ks = 0; ks < 32; ++ks) {
      const int colpart = ((((ks << 2) | q) ^ akey) << 3);
      const f16x8 a0 = __builtin_bit_cast(f16x8, *(const s16x8*)&st[(0 * 16 + ccol) * HD + colpart]);
      const f16x8 a1 = __builtin_bit_cast(f16x8, *(const s16x8*)&st[(1 * 16 + ccol) * HD + colpart]);
#pragma unroll
      for (int ct = 0; ct < 8; ++ct) {
        const long boff = (((long)ks * NJT + jt0 + ct) * 64 + l) * 8;
        const f16x8 bh = __builtin_bit_cast(f16x8, *(const s16x8*)(wph + boff));
        acc[0][ct] = MFMAH(a0, bh, acc[0][ct]);
        acc[1][ct] = MFMAH(a1, bh, acc[1][ct]);
      }
    }
    __builtin_amdgcn_s_setprio(0);
    __syncthreads();  // all plane reads done
    // Writeback: plane <- fp16(acc) (pure LDS, no global loads).
#pragma unroll
    for (int rt = 0; rt < 2; ++rt)
#pragma unroll
      for (int ct = 0; ct < 8; ++ct) {
        const int colb = (jt0 + ct) * 16 + ccol;
        const int cb7 = colb & 7;
        const int cblk = colb >> 3;
#pragma unroll
        for (int r = 0; r < 4; ++r) {
          const int row = rt * 16 + q * 4 + r;
          const f16 hv = (f16)acc[rt][ct][r];
          const int si = row * HD + (((cblk ^ (row & 15)) << 3) | cb7);
          st[si] = __builtin_bit_cast(u16, hv);
        }
      }
    __syncthreads();
    // Sweep: v = plane + projS[t]*inv_s (contiguous loads); plane <- fp16(v);
    // EMIT: out1[t], out2[t] <- v*s (out2 write aliases the projS[t] load --
    // same thread, same address, load-before-store by dataflow).
#pragma unroll
    for (int it = 0; it < 8; ++it) {
      const int idx = tid + it * 512;
      const int r = idx >> 7;
      const int cb8 = (idx & 127) << 3;
      const int n = g * 32 + r;
      const int si = r * HD + (((cb8 >> 3) ^ (r & 15)) << 3);
      const s16x8 av = *(const s16x8*)&st[si];
      const long po = ((long)n * TS + t) * HD + cb8;
      const f32x4 p0 = ntl4(projS + po);
      const f32x4 p1 = ntl4(projS + po + 4);
      float v[8];
      v[0] = (float)__builtin_bit_cast(f16, (u16)av[0]) + p0[0] * inv_s;
      v[1] = (float)__builtin_bit_cast(f16, (u16)av[1]) + p0[1] * inv_s;
      v[2] = (float)__builtin_bit_cast(f16, (u16)av[2]) + p0[2] * inv_s;
      v[3] = (float)__builtin_bit_cast(f16, (u16)av[3]) + p0[3] * inv_s;
      v[4] = (float)__builtin_bit_cast(f16, (u16)av[4]) + p1[0] * inv_s;
      v[5] = (float)__builtin_bit_cast(f16, (u16)av[5]) + p1[1] * inv_s;
      v[6] = (float)__builtin_bit_cast(f16, (u16)av[6]) + p1[2] * inv_s;
      v[7] = (float)__builtin_bit_cast(f16, (u16)av[7]) + p1[3] * inv_s;
      s16x8 nv;
#pragma unroll
      for (int j2 = 0; j2 < 8; ++j2)
        nv[j2] = (short)__builtin_bit_cast(u16, (f16)v[j2]);
      *(s16x8*)&st[si] = nv;
      if constexpr (EMIT) {
        f32x4 o0, o1;
        o0[0] = v[0] * s; o0[1] = v[1] * s; o0[2] = v[2] * s; o0[3] = v[3] * s;
        o1[0] = v[4] * s; o1[1] = v[5] * s; o1[2] = v[6] * s; o1[3] = v[7] * s;
        nts4(o0, out1 + po);
        nts4(o1, out1 + po + 4);
        nts4(o0, out2 + po);
        nts4(o1, out2 + po + 4);
      }
    }
    __syncthreads();
  }
  if constexpr (!EMIT) {
    for (int i = tid; i < 32 * HD; i += 512) {
      const int r = i >> 10;
      const int col = i & (HD - 1);
      const int si = r * HD + ((((col >> 3) ^ (r & 15)) << 3) | (col & 7));
      const float v = (float)__builtin_bit_cast(f16, st[si]);
      u16 hh, ll; split2(v, hh, ll);
      const long o = ((long)c * NB + g * 32 + r) * HD + col;
      ebh[o] = hh;
      ebl[o] = ll;
    }
  }
}

// ---------------- host ----------------

extern "C" void kernel_launch(void* const* d_in, const int* in_sizes, int n_in,
                              void* d_out, int out_size, void* d_ws, size_t ws_size,
                              hipStream_t stream) {
  const float* x = (const float*)d_in[0];
  const float* w_ih = (const float*)d_in[1];
  const float* b_ih = (const float*)d_in[2];
  const float* w_hh = (const float*)d_in[3];
  const float* initial = (const float*)d_in[4];

  char* r1 = (char*)d_out;  // out copy 1: scratch until phase D
  float* out1 = (float*)d_out;
  float* projS = out1 + (long)NB * TS * HD;  // out copy 2: shifted proj, then out2 in-place
  float* out2 = projS;

  // region-1 scratch (all dead before phase D). x ping = e planes.
  u16* xph = (u16*)(r1 + 0L);                          // 32 MB (128 chunk states hi)
  u16* xpl = (u16*)(r1 + 33554432L);                   // 32 MB (lo)
  u16* xqh = (u16*)(r1 + 67108864L);                   // 32 MB pong hi
  u16* xql = (u16*)(r1 + 100663296L);                  // 32 MB pong lo
  u16* wt_pk_h = (u16*)(r1 + 134217728L);              // W^T bf16 pack
  u16* wt_pk_l = (u16*)(r1 + 136314880L);
  u16* wt_rm_h = (u16*)(r1 + 138412032L);
  u16* wt_rm_l = (u16*)(r1 + 140509184L);
  u16* rm_pp_h[2] = {(u16*)(r1 + 142606336L), (u16*)(r1 + 146800640L)};
  u16* rm_pp_l[2] = {(u16*)(r1 + 144703488L), (u16*)(r1 + 148897792L)};
  u16* pk_pp_h[2] = {(u16*)(r1 + 150994944L), (u16*)(r1 + 155189248L)};
  u16* pk_pp_l[2] = {(u16*)(r1 + 153092096L), (u16*)(r1 + 157286400L)};
  u16* wih_h = (u16*)(r1 + 159383552L);
  u16* wih_l = (u16*)(r1 + 159645696L);
  u16* wp_pk_h[7];
  u16* wp_pk_l[7];
  for (int j = 0; j < 7; ++j) {
    wp_pk_h[j] = (u16*)(r1 + 161480704L + (long)j * 4194304L);
    wp_pk_l[j] = (u16*)(r1 + 161480704L + (long)j * 4194304L + 2097152L);
  }

  // d_ws: survives into phase D
  char* wsb = (char*)d_ws;
  u16* wt16_h = (u16*)(wsb + 0L);                      // fp16 W^T pack (single)
  u16* zbuf = (u16*)(wsb + 4194304L);                  // bf16 Z, 127 slots
  u32* zmx = (u32*)(wsb + 37486592L);                  // 128 u32

  (void)hipMemsetAsync(zmx, 0, 512, stream);

  // prep: packs + rm planes
  k_pack_b<<<512, 256, 0, stream>>>(w_hh, 1L, (long)HD, NJT, 32 * NJT * 64, wt_pk_h, wt_pk_l);
  k_pack_f16<<<512, 256, 0, stream>>>(w_hh, 1L, (long)HD, NJT, 32 * NJT * 64, wt16_h);
  k_pack_b<<<64, 256, 0, stream>>>(w_ih, 1L, (long)ID, NJT, 4 * NJT * 64, wih_h, wih_l);
  k_split_strided<<<4096, 256, 0, stream>>>(w_hh, 1L, (long)HD, HD, (long)HD * HD, wt_rm_h, wt_rm_l);

  // phase A: projS[t+1] = x[:,t] @ w_ih^T + b_ih (time-shifted store)
  dim3 gproj(2048, 8);
  k_gemm3<1, 4, 4, 1><<<gproj, 256, 0, stream>>>(
      nullptr, nullptr, x, (long)ID, wih_h, wih_l, ID / 32,
      b_ih, projS, (long)HD, nullptr, nullptr, nullptr, nullptr,
      nullptr, nullptr, nullptr, nullptr, 0);

  // Squaring chain: 10 squarings W -> W^1024 (all in W^T space).
  // i=3 produces W^16 (pk -> wp_pk[0], d=1); i=4..9 -> wp_pk[1..6].
  const u16 *arh = wt_rm_h, *arl = wt_rm_l, *aph = wt_pk_h, *apl = wt_pk_l;
  dim3 g1616(16, 16);
  for (int i = 0; i < 10; ++i) {
    u16* orh = rm_pp_h[i & 1];
    u16* orl = rm_pp_l[i & 1];
    u16* oph = (i >= 3) ? wp_pk_h[i - 3] : pk_pp_h[i & 1];
    u16* opl = (i >= 3) ? wp_pk_l[i - 3] : pk_pp_l[i & 1];
    k_gemm3<3, 2, 2, 0><<<g1616, 256, 0, stream>>>(
        arh, arl, nullptr, (long)HD, aph, apl, HD / 32,
        nullptr, nullptr, 0L, orh, orl, oph, opl,
        nullptr, nullptr, nullptr, nullptr, 0);
    arh = orh; arl = orl; aph = oph; apl = opl;
  }

  // phase B: per-chunk local scans -> e_c planes (= KS ping buffer)
  k_scan2<0><<<512, 512, 0, stream>>>(projS, initial, wt16_h,
                                      nullptr, nullptr, xph, xpl, nullptr, nullptr);

  // phase C: Kogge-Stone inclusive scan over 128 chunk states (7 rounds,
  // barrier-free; one fused launch per round incl. pass-through copies).
  const u16 *xin_h = xph, *xin_l = xpl;
  u16 *xout_h = xqh, *xout_l = xql;
  for (int j = 0; j < 7; ++j) {
    const int d = 1 << j;
    dim3 gks(CCH, 8);
    k_gemm3<4, 4, 4, 0><<<gks, 256, 0, stream>>>(
        xin_h, xin_l, nullptr, (long)HD, wp_pk_h[j], wp_pk_l[j], HD / 32,
        nullptr, nullptr, 0L, xout_h, xout_l,
        nullptr, nullptr, nullptr, nullptr, xin_h, xin_l, d);
    const u16* th = xin_h; const u16* tl = xin_l;
    xin_h = xout_h; xin_l = xout_l;
    xout_h = (u16*)th; xout_l = (u16*)tl;
  }
  // final states in xin_h/xin_l

  // Z-inits: Z_c = S_{c-1} * W^T + projS[:, c*16], c = 1..127 -> bf16 zbuf
  // + per-chunk absmax into zmx.
  dim3 gz(127, 8);
  k_gemm3<2, 4, 4, 0><<<gz, 256, 0, stream>>>(
      xin_h, xin_l, nullptr, (long)HD, wt_pk_h, wt_pk_l, HD / 32,
      projS, nullptr, 0L, nullptr, nullptr, nullptr, nullptr,
      zbuf, zmx, nullptr, nullptr, 0);

  // phase D: emit all hidden states into out1 AND out2 (in-place over projS)
  k_scan2<1><<<512, 512, 0, stream>>>(projS, initial, wt16_h,
                                      zbuf, zmx, nullptr, nullptr, out1, out2);
}

// Round 14
// 4658.304 us; speedup vs baseline: 1.1829x; 1.1829x over previous
//
// Chunked parallel linear-RNN scan for MI355X (gfx950).
//   projS[t] = x[:,t-1] @ w_ih^T + b_ih  (TIME-SHIFTED projection)
//   h_t  = h_{t-1} @ w_hh^T + projS[t]   (chunked scan)
// R14 = R12 (proven 4.80 ms; R13's 2-block/CU retile regressed and is
// reverted) + lgkmcnt-only step barriers in k_scan2: __syncthreads drains
// vmcnt(0), serializing ~96MB/step of in-flight NT output stores against the
// next MFMA phase; the step barriers only need LDS visibility. Inline-asm
// s_waitcnt lgkmcnt(0) + s_barrier, sched_barrier-fenced (guide rule #18).
// Values bit-identical to R12.

#include <hip/hip_runtime.h>
#include <stdint.h>

typedef unsigned int u32;
typedef unsigned short u16;
typedef _Float16 f16;
typedef __attribute__((ext_vector_type(4))) float f32x4;
typedef __attribute__((ext_vector_type(8))) short s16x8;
typedef __attribute__((ext_vector_type(8))) _Float16 f16x8;

#define NB 128
#define TS 2048
#define ID 128
#define HD 1024
#define LCH 16
#define CCH 128
#define NJT 64  // HD/16

__device__ __forceinline__ u16 f2bf(float f) {
  u32 u = __builtin_bit_cast(u32, f);
  u += 0x7FFFu + ((u >> 16) & 1u);
  return (u16)(u >> 16);
}
__device__ __forceinline__ float bf2f(u16 h) {
  u32 u = ((u32)h) << 16;
  return __builtin_bit_cast(float, u);
}
__device__ __forceinline__ void split2(float f, u16& hi, u16& lo) {
  hi = f2bf(f);
  lo = f2bf(f - bf2f(hi));
}
__device__ __forceinline__ float ntl(const float* p) { return __builtin_nontemporal_load(p); }
__device__ __forceinline__ f32x4 ntl4(const float* p) {
  return __builtin_nontemporal_load((const f32x4*)p);
}
__device__ __forceinline__ void nts(float v, float* p) { __builtin_nontemporal_store(v, p); }
__device__ __forceinline__ void nts4(f32x4 v, float* p) {
  __builtin_nontemporal_store(v, (f32x4*)p);
}
// LDS-only barrier: waits lgkmcnt(0) (LDS visibility) but lets VMEM NT
// stores stay in flight across the barrier (no vmcnt drain).
__device__ __forceinline__ void bar_lgkm() {
  __builtin_amdgcn_sched_barrier(0);
  asm volatile("s_waitcnt lgkmcnt(0)" ::: "memory");
  __builtin_amdgcn_s_barrier();
  __builtin_amdgcn_sched_barrier(0);
}
#define MFMA16(a, b, c) __builtin_amdgcn_mfma_f32_16x16x32_bf16((a), (b), (c), 0, 0, 0)
#define MFMAH(a, b, c) __builtin_amdgcn_mfma_f32_16x16x32_f16((a), (b), (c), 0, 0, 0)

// ---------------- prep kernels ----------------

// Pack B[k][j] = src[k*sk + j*sj] into MFMA-fragment order (bf16 hi/lo).
__global__ void k_pack_b(const float* __restrict__ src, long sk, long sj, int jtiles,
                         int total, u16* __restrict__ dh, u16* __restrict__ dl) {
  const int fid = blockIdx.x * blockDim.x + threadIdx.x;
  if (fid >= total) return;
  const int lane = fid & 63;
  const int tt = fid >> 6;
  const int jt = tt % jtiles;
  const int kt = tt / jtiles;
  const int k0 = kt * 32 + (lane >> 4) * 8;
  const long j = jt * 16 + (lane & 15);
  s16x8 hv, lv;
#pragma unroll
  for (int i = 0; i < 8; ++i) {
    const float v = src[(long)(k0 + i) * sk + j * sj];
    u16 hh, ll; split2(v, hh, ll);
    hv[i] = (short)hh; lv[i] = (short)ll;
  }
  *(s16x8*)(dh + (long)fid * 8) = hv;
  *(s16x8*)(dl + (long)fid * 8) = lv;
}

// Pack single-fp16 plane (round-to-nearest fp16 of W).
__global__ void k_pack_f16(const float* __restrict__ src, long sk, long sj, int jtiles,
                           int total, u16* __restrict__ dh) {
  const int fid = blockIdx.x * blockDim.x + threadIdx.x;
  if (fid >= total) return;
  const int lane = fid & 63;
  const int tt = fid >> 6;
  const int jt = tt % jtiles;
  const int kt = tt / jtiles;
  const int k0 = kt * 32 + (lane >> 4) * 8;
  const long j = jt * 16 + (lane & 15);
  s16x8 hv;
#pragma unroll
  for (int i = 0; i < 8; ++i) {
    const float v = src[(long)(k0 + i) * sk + j * sj];
    const f16 hh = (f16)v;
    hv[i] = (short)__builtin_bit_cast(u16, hh);
  }
  *(s16x8*)(dh + (long)fid * 8) = hv;
}

// Split to row-major bf16 hi/lo planes.
__global__ void k_split_strided(const float* __restrict__ src, long sk, long sj, int nj,
                                long total, u16* __restrict__ dh, u16* __restrict__ dl) {
  const long i = (long)blockIdx.x * blockDim.x + threadIdx.x;
  if (i >= total) return;
  const long k = i / nj;
  const long j = i % nj;
  u16 hh, ll;
  split2(src[k * sk + j * sj], hh, ll);
  dh[i] = hh;
  dl[i] = ll;
}

// ---------------- generic bf16x3 GEMM ----------------
// C[m,n] = sum_k A[m,k]*B[k,n]. Block (32*RT)x(32*CT), 4 waves 2x2.
// ASRC 0: A from pre-split rm planes. 1: A from fp32 (split on the fly).
// EPI 1: +bias(aux), LDS-coalesced NT store to cout, TIME-SHIFTED:
//        row (n,t) stored at projS slot t+1 (t<TS-1); t==0 also at slot 0.
// EPI 2: Z-init: z = v + projS-gather(aux); zb16 <- bf16(z); atomicMax per
//        chunk into zmx.
// EPI 3: write rm bf16 hi/lo planes AND packed bf16 hi/lo planes.
// EPI 4: fused Kogge-Stone round (ksd = d): blocks with blockIdx.x < d copy
//        ein tile -> drm tile; else out[C] = A[C-d]*B + ein[C] (split planes).
template <int EPI, int RT, int CT, int ASRC>
__global__ __launch_bounds__(256) void k_gemm3(
    const u16* __restrict__ ahi, const u16* __restrict__ alo,
    const float* __restrict__ af32, long lda,
    const u16* __restrict__ bhi, const u16* __restrict__ blo, int ksteps,
    const float* __restrict__ aux, float* __restrict__ cout, long ldc,
    u16* __restrict__ drm_h, u16* __restrict__ drm_l,
    u16* __restrict__ dpk_h, u16* __restrict__ dpk_l,
    u16* __restrict__ zb16, u32* __restrict__ zmx,
    const u16* __restrict__ einh, const u16* __restrict__ einl, int ksd) {
  __shared__ float cb[4][16][33];
  const int tid = threadIdx.x;
  const int l = tid & 63;
  const int w = tid >> 6;
  const int wr = w >> 1, wc = w & 1;
  const int n0 = blockIdx.y * (32 * CT) + wc * (16 * CT);
  if constexpr (EPI == 4) {
    if ((int)blockIdx.x < ksd) {
      // pass-through: copy ein tile -> drm tile
      const long rbase = (long)blockIdx.x * (32 * RT);
      const int ncols8 = (32 * CT) / 8;
      const int nb0 = blockIdx.y * (32 * CT);
      for (int i = tid; i < (32 * RT) * ncols8; i += 256) {
        const int rr = i / ncols8;
        const int cc = (i % ncols8) * 8;
        const long o = (rbase + rr) * HD + nb0 + cc;
        *(s16x8*)(drm_h + o) = *(const s16x8*)(einh + o);
        *(s16x8*)(drm_l + o) = *(const s16x8*)(einl + o);
      }
      return;
    }
  }
  const long m0 = ((long)blockIdx.x - ((EPI == 4) ? ksd : 0)) * (32 * RT) + wr * (16 * RT);
  const int arow = l & 15, koff = (l >> 4) * 8;
  f32x4 acc[RT][CT];
#pragma unroll
  for (int a = 0; a < RT; ++a)
#pragma unroll
    for (int b = 0; b < CT; ++b) acc[a][b] = (f32x4){0.f, 0.f, 0.f, 0.f};
#pragma unroll 1
  for (int ks = 0; ks < ksteps; ++ks) {
    s16x8 AH[RT], AL[RT], BH[CT], BL[CT];
#pragma unroll
    for (int rt = 0; rt < RT; ++rt) {
      const long off = (m0 + rt * 16 + arow) * lda + ks * 32 + koff;
      if constexpr (ASRC == 0) {
        AH[rt] = *(const s16x8*)(ahi + off);
        AL[rt] = *(const s16x8*)(alo + off);
      } else {
        const float4 f0 = *(const float4*)(af32 + off);
        const float4 f1 = *(const float4*)(af32 + off + 4);
        float fv[8] = {f0.x, f0.y, f0.z, f0.w, f1.x, f1.y, f1.z, f1.w};
        s16x8 hv, lv;
#pragma unroll
        for (int i = 0; i < 8; ++i) {
          u16 hh, ll; split2(fv[i], hh, ll);
          hv[i] = (short)hh; lv[i] = (short)ll;
        }
        AH[rt] = hv; AL[rt] = lv;
      }
    }
#pragma unroll
    for (int ct = 0; ct < CT; ++ct) {
      const long off = (((long)ks * NJT + (n0 >> 4) + ct) * 64 + l) * 8;
      BH[ct] = *(const s16x8*)(bhi + off);
      BL[ct] = *(const s16x8*)(blo + off);
    }
#pragma unroll
    for (int ct = 0; ct < CT; ++ct)
#pragma unroll
      for (int rt = 0; rt < RT; ++rt) {
        acc[rt][ct] = MFMA16(AH[rt], BH[ct], acc[rt][ct]);
        acc[rt][ct] = MFMA16(AL[rt], BH[ct], acc[rt][ct]);
        acc[rt][ct] = MFMA16(AH[rt], BL[ct], acc[rt][ct]);
      }
  }
  const int crow = (l >> 4) * 4, ccol = l & 15;
  if constexpr (EPI == 1) {
#pragma unroll
    for (int rt = 0; rt < RT; ++rt)
#pragma unroll
      for (int ctp = 0; ctp < CT / 2; ++ctp) {
#pragma unroll
        for (int e = 0; e < 2; ++e)
#pragma unroll
          for (int r = 0; r < 4; ++r)
            cb[w][crow + r][e * 16 + ccol] = acc[rt][2 * ctp + e][r];
        const int rr = l >> 2, c8 = (l & 3) * 8;
        const int colg = n0 + ctp * 32 + c8;
        const float4 b0 = *(const float4*)&aux[colg];
        const float4 b1 = *(const float4*)&aux[colg + 4];
        f32x4 v0, v1;
        v0[0] = cb[w][rr][c8 + 0] + b0.x; v0[1] = cb[w][rr][c8 + 1] + b0.y;
        v0[2] = cb[w][rr][c8 + 2] + b0.z; v0[3] = cb[w][rr][c8 + 3] + b0.w;
        v1[0] = cb[w][rr][c8 + 4] + b1.x; v1[1] = cb[w][rr][c8 + 5] + b1.y;
        v1[2] = cb[w][rr][c8 + 6] + b1.z; v1[3] = cb[w][rr][c8 + 7] + b1.w;
        const long row = m0 + rt * 16 + rr;
        const int t = (int)(row & (TS - 1));
        if (t != TS - 1) {
          nts4(v0, cout + (row + 1) * ldc + colg);
          nts4(v1, cout + (row + 1) * ldc + colg + 4);
        }
        if (t == 0) {
          nts4(v0, cout + row * ldc + colg);
          nts4(v1, cout + row * ldc + colg + 4);
        }
      }
  } else if constexpr (EPI == 2) {
    float mym = 0.f;
#pragma unroll
    for (int rt = 0; rt < RT; ++rt)
#pragma unroll
      for (int ct = 0; ct < CT; ++ct) {
        const int col = n0 + ct * 16 + ccol;
#pragma unroll
        for (int r = 0; r < 4; ++r) {
          const long row = m0 + rt * 16 + crow + r;
          const int slot = (int)(row >> 7);      // chunk c-1
          const int n = (int)(row & 127);
          const float z = acc[rt][ct][r] +
              aux[((long)n * TS + (long)(slot + 1) * LCH) * HD + col];
          zb16[((long)slot * NB + n) * HD + col] = f2bf(z);
          mym = fmaxf(mym, fabsf(z));
        }
      }
#pragma unroll
    for (int d = 1; d < 64; d <<= 1) mym = fmaxf(mym, __shfl_xor(mym, d));
    if (l == 0) {
      const int slot = (int)(m0 >> 7);
      atomicMax(&zmx[slot + 1], __builtin_bit_cast(u32, mym));
    }
  } else if constexpr (EPI == 4) {
    const long rshift = (long)ksd * (32 * RT);
#pragma unroll
    for (int rt = 0; rt < RT; ++rt)
#pragma unroll
      for (int ct = 0; ct < CT; ++ct) {
        const int col = n0 + ct * 16 + ccol;
#pragma unroll
        for (int r = 0; r < 4; ++r) {
          const long row = m0 + rt * 16 + crow + r;
          const long o = (row + rshift) * HD + col;
          const float v = acc[rt][ct][r] + bf2f(einh[o]) + bf2f(einl[o]);
          u16 hh, ll; split2(v, hh, ll);
          drm_h[o] = hh;
          drm_l[o] = ll;
        }
      }
  } else {
#pragma unroll
    for (int rt = 0; rt < RT; ++rt)
#pragma unroll
      for (int ct = 0; ct < CT; ++ct) {
        const int col = n0 + ct * 16 + ccol;
#pragma unroll
        for (int r = 0; r < 4; ++r) {
          const long row = m0 + rt * 16 + crow + r;
          const float v = acc[rt][ct][r];
          u16 hh, ll; split2(v, hh, ll);
          drm_h[row * HD + col] = hh;
          drm_l[row * HD + col] = ll;
          const int lane2 = ((((int)row >> 3) & 3) << 4) | (col & 15);
          const long poff = (((row >> 5) * NJT + (col >> 4)) * 64 + lane2) * 8 + (row & 7);
          dpk_h[poff] = hh;
          dpk_l[poff] = ll;
        }
      }
  }
}

// ---------------- phases B / D: per-chunk fp16 scan ----------------
// 256 blocks = 128 chunks x 2 row-halves of 64; 16 waves (4/SIMD).
// State: single fp16 plane [64][1024] in LDS (128 KiB), r&15 swizzle.
// W: SINGLE fp16 pack (2MB -> L2-resident per XCD). Step = { MFMA } ->
// bar_lgkm -> { writeback plane } -> bar_lgkm -> { sweep: v = plane +
// projS[t]*inv_s; EMIT: out1[t], out2[t] <- v*s (out2 in-place over projS,
// dataflow-ordered) } -> bar_lgkm (NT stores drain under next MFMA).
template <int EMIT>
__global__ __launch_bounds__(1024, 4) __attribute__((amdgpu_waves_per_eu(4, 4)))
void k_scan2(
    const float* __restrict__ projS, const float* __restrict__ initial,
    const u16* __restrict__ wph,
    const u16* __restrict__ zbuf, const u32* __restrict__ zmx,
    u16* __restrict__ ebh, u16* __restrict__ ebl,
    float* __restrict__ out1, float* __restrict__ out2) {
  __shared__ u16 st[64 * HD];
  const int b = blockIdx.x;
  const int c = b >> 1;
  const int g = b & 1;
  const int tid = threadIdx.x;
  const int l = tid & 63;
  const int w = tid >> 6;  // 0..15
  const long t0 = (long)c * LCH;
  const int ccol = l & 15;
  const int q = l >> 4;
  const int jt0 = w * 4;   // 4 col-tiles (64 cols) per wave
  const int akey = l & 15;

  float s = 1.f, inv_s = 1.f;
  if constexpr (EMIT) {
    const u32 zb = zmx[c];
    const int ex = (int)((zb >> 23) & 255u) - 127;
    const int k = ex > 8 ? ex - 8 : 0;
    s = __builtin_bit_cast(float, (u32)(127 + k) << 23);
    inv_s = __builtin_bit_cast(float, (u32)(127 - k) << 23);
  }

  // Init state plane (+ for EMIT, emit out[t0] -- out2[t0] overwrite of
  // projS[t0] is safe: nothing reads projS[t0] afterwards).
  for (int i = tid; i < 64 * HD; i += 1024) {
    const int r = i >> 10;
    const int col = i & (HD - 1);
    const int n = g * 64 + r;
    float v;
    if (c == 0) {
      v = ntl(initial + (long)n * HD + col) + ntl(projS + ((long)n * TS) * HD + col);
    } else {
      if constexpr (EMIT) v = bf2f(zbuf[((long)(c - 1) * NB + n) * HD + col]);
      else                v = ntl(projS + ((long)n * TS + t0) * HD + col);
    }
    const f16 hv = (f16)(v * inv_s);
    const int si = r * HD + ((((col >> 3) ^ (r & 15)) << 3) | (col & 7));
    st[si] = __builtin_bit_cast(u16, hv);
    if constexpr (EMIT) {
      const long o = ((long)n * TS + t0) * HD + col;
      nts(v, out1 + o);
      nts(v, out2 + o);
    }
  }
  bar_lgkm();

#pragma unroll 1
  for (int step = 1; step < LCH; ++step) {
    const long t = t0 + step;
    f32x4 acc[4][4];
#pragma unroll
    for (int rt = 0; rt < 4; ++rt)
#pragma unroll
      for (int ct = 0; ct < 4; ++ct) acc[rt][ct] = (f32x4){0.f, 0.f, 0.f, 0.f};
    __builtin_amdgcn_s_setprio(1);
#pragma unroll 2
    for (int ks = 0; ks < 32; ++ks) {
      const int colpart = ((((ks << 2) | q) ^ akey) << 3);
      const f16x8 a0 = __builtin_bit_cast(f16x8, *(const s16x8*)&st[(0 * 16 + ccol) * HD + colpart]);
      const f16x8 a1 = __builtin_bit_cast(f16x8, *(const s16x8*)&st[(1 * 16 + ccol) * HD + colpart]);
      const f16x8 a2 = __builtin_bit_cast(f16x8, *(const s16x8*)&st[(2 * 16 + ccol) * HD + colpart]);
      const f16x8 a3 = __builtin_bit_cast(f16x8, *(const s16x8*)&st[(3 * 16 + ccol) * HD + colpart]);
#pragma unroll
      for (int ct = 0; ct < 4; ++ct) {
        const long boff = (((long)ks * NJT + jt0 + ct) * 64 + l) * 8;
        const f16x8 bh = __builtin_bit_cast(f16x8, *(const s16x8*)(wph + boff));
        acc[0][ct] = MFMAH(a0, bh, acc[0][ct]);
        acc[1][ct] = MFMAH(a1, bh, acc[1][ct]);
        acc[2][ct] = MFMAH(a2, bh, acc[2][ct]);
        acc[3][ct] = MFMAH(a3, bh, acc[3][ct]);
      }
    }
    __builtin_amdgcn_s_setprio(0);
    bar_lgkm();  // all plane reads latched; NT stores may still be in flight
    // Writeback: plane <- fp16(acc) (pure LDS, no global loads).
#pragma unroll
    for (int rt = 0; rt < 4; ++rt)
#pragma unroll
      for (int ct = 0; ct < 4; ++ct) {
        const int colb = (jt0 + ct) * 16 + ccol;
        const int cb7 = colb & 7;
        const int cblk = colb >> 3;
#pragma unroll
        for (int r = 0; r < 4; ++r) {
          const int row = rt * 16 + q * 4 + r;
          const f16 hv = (f16)acc[rt][ct][r];
          const int si = row * HD + (((cblk ^ (row & 15)) << 3) | cb7);
          st[si] = __builtin_bit_cast(u16, hv);
        }
      }
    bar_lgkm();
    // Sweep: v = plane + projS[t]*inv_s (contiguous loads); plane <- fp16(v);
    // EMIT: out1[t], out2[t] <- v*s (out2 write aliases the projS[t] load --
    // same thread, same address, load-before-store by dataflow).
#pragma unroll
    for (int it = 0; it < 8; ++it) {
      const int idx = tid + it * 1024;
      const int r = idx >> 7;
      const int cb8 = (idx & 127) << 3;
      const int n = g * 64 + r;
      const int si = r * HD + (((cb8 >> 3) ^ (r & 15)) << 3);
      const s16x8 av = *(const s16x8*)&st[si];
      const long po = ((long)n * TS + t) * HD + cb8;
      const f32x4 p0 = ntl4(projS + po);
      const f32x4 p1 = ntl4(projS + po + 4);
      float v[8];
      v[0] = (float)__builtin_bit_cast(f16, (u16)av[0]) + p0[0] * inv_s;
      v[1] = (float)__builtin_bit_cast(f16, (u16)av[1]) + p0[1] * inv_s;
      v[2] = (float)__builtin_bit_cast(f16, (u16)av[2]) + p0[2] * inv_s;
      v[3] = (float)__builtin_bit_cast(f16, (u16)av[3]) + p0[3] * inv_s;
      v[4] = (float)__builtin_bit_cast(f16, (u16)av[4]) + p1[0] * inv_s;
      v[5] = (float)__builtin_bit_cast(f16, (u16)av[5]) + p1[1] * inv_s;
      v[6] = (float)__builtin_bit_cast(f16, (u16)av[6]) + p1[2] * inv_s;
      v[7] = (float)__builtin_bit_cast(f16, (u16)av[7]) + p1[3] * inv_s;
      s16x8 nv;
#pragma unroll
      for (int j2 = 0; j2 < 8; ++j2)
        nv[j2] = (short)__builtin_bit_cast(u16, (f16)v[j2]);
      *(s16x8*)&st[si] = nv;
      if constexpr (EMIT) {
        f32x4 o0, o1;
        o0[0] = v[0] * s; o0[1] = v[1] * s; o0[2] = v[2] * s; o0[3] = v[3] * s;
        o1[0] = v[4] * s; o1[1] = v[5] * s; o1[2] = v[6] * s; o1[3] = v[7] * s;
        nts4(o0, out1 + po);
        nts4(o1, out1 + po + 4);
        nts4(o0, out2 + po);
        nts4(o1, out2 + po + 4);
      }
    }
    bar_lgkm();  // plane writes visible; output NT stores drain under next MFMA
  }
  if constexpr (!EMIT) {
    for (int i = tid; i < 64 * HD; i += 1024) {
      const int r = i >> 10;
      const int col = i & (HD - 1);
      const int si = r * HD + ((((col >> 3) ^ (r & 15)) << 3) | (col & 7));
      const float v = (float)__builtin_bit_cast(f16, st[si]);
      u16 hh, ll; split2(v, hh, ll);
      const long o = ((long)c * NB + g * 64 + r) * HD + col;
      ebh[o] = hh;
      ebl[o] = ll;
    }
  }
}

// ---------------- host ----------------

extern "C" void kernel_launch(void* const* d_in, const int* in_sizes, int n_in,
                              void* d_out, int out_size, void* d_ws, size_t ws_size,
                              hipStream_t stream) {
  const float* x = (const float*)d_in[0];
  const float* w_ih = (const float*)d_in[1];
  const float* b_ih = (const float*)d_in[2];
  const float* w_hh = (const float*)d_in[3];
  const float* initial = (const float*)d_in[4];

  char* r1 = (char*)d_out;  // out copy 1: scratch until phase D
  float* out1 = (float*)d_out;
  float* projS = out1 + (long)NB * TS * HD;  // out copy 2: shifted proj, then out2 in-place
  float* out2 = projS;

  // region-1 scratch (all dead before phase D). x ping = e planes.
  u16* xph = (u16*)(r1 + 0L);                          // 32 MB (128 chunk states hi)
  u16* xpl = (u16*)(r1 + 33554432L);                   // 32 MB (lo)
  u16* xqh = (u16*)(r1 + 67108864L);                   // 32 MB pong hi
  u16* xql = (u16*)(r1 + 100663296L);                  // 32 MB pong lo
  u16* wt_pk_h = (u16*)(r1 + 134217728L);              // W^T bf16 pack
  u16* wt_pk_l = (u16*)(r1 + 136314880L);
  u16* wt_rm_h = (u16*)(r1 + 138412032L);
  u16* wt_rm_l = (u16*)(r1 + 140509184L);
  u16* rm_pp_h[2] = {(u16*)(r1 + 142606336L), (u16*)(r1 + 146800640L)};
  u16* rm_pp_l[2] = {(u16*)(r1 + 144703488L), (u16*)(r1 + 148897792L)};
  u16* pk_pp_h[2] = {(u16*)(r1 + 150994944L), (u16*)(r1 + 155189248L)};
  u16* pk_pp_l[2] = {(u16*)(r1 + 153092096L), (u16*)(r1 + 157286400L)};
  u16* wih_h = (u16*)(r1 + 159383552L);
  u16* wih_l = (u16*)(r1 + 159645696L);
  u16* wp_pk_h[7];
  u16* wp_pk_l[7];
  for (int j = 0; j < 7; ++j) {
    wp_pk_h[j] = (u16*)(r1 + 161480704L + (long)j * 4194304L);
    wp_pk_l[j] = (u16*)(r1 + 161480704L + (long)j * 4194304L + 2097152L);
  }

  // d_ws: survives into phase D
  char* wsb = (char*)d_ws;
  u16* wt16_h = (u16*)(wsb + 0L);                      // fp16 W^T pack (single)
  u16* zbuf = (u16*)(wsb + 4194304L);                  // bf16 Z, 127 slots
  u32* zmx = (u32*)(wsb + 37486592L);                  // 128 u32

  (void)hipMemsetAsync(zmx, 0, 512, stream);

  // prep: packs + rm planes
  k_pack_b<<<512, 256, 0, stream>>>(w_hh, 1L, (long)HD, NJT, 32 * NJT * 64, wt_pk_h, wt_pk_l);
  k_pack_f16<<<512, 256, 0, stream>>>(w_hh, 1L, (long)HD, NJT, 32 * NJT * 64, wt16_h);
  k_pack_b<<<64, 256, 0, stream>>>(w_ih, 1L, (long)ID, NJT, 4 * NJT * 64, wih_h, wih_l);
  k_split_strided<<<4096, 256, 0, stream>>>(w_hh, 1L, (long)HD, HD, (long)HD * HD, wt_rm_h, wt_rm_l);

  // phase A: projS[t+1] = x[:,t] @ w_ih^T + b_ih (time-shifted store)
  dim3 gproj(2048, 8);
  k_gemm3<1, 4, 4, 1><<<gproj, 256, 0, stream>>>(
      nullptr, nullptr, x, (long)ID, wih_h, wih_l, ID / 32,
      b_ih, projS, (long)HD, nullptr, nullptr, nullptr, nullptr,
      nullptr, nullptr, nullptr, nullptr, 0);

  // Squaring chain: 10 squarings W -> W^1024 (all in W^T space).
  // i=3 produces W^16 (pk -> wp_pk[0], d=1); i=4..9 -> wp_pk[1..6].
  const u16 *arh = wt_rm_h, *arl = wt_rm_l, *aph = wt_pk_h, *apl = wt_pk_l;
  dim3 g1616(16, 16);
  for (int i = 0; i < 10; ++i) {
    u16* orh = rm_pp_h[i & 1];
    u16* orl = rm_pp_l[i & 1];
    u16* oph = (i >= 3) ? wp_pk_h[i - 3] : pk_pp_h[i & 1];
    u16* opl = (i >= 3) ? wp_pk_l[i - 3] : pk_pp_l[i & 1];
    k_gemm3<3, 2, 2, 0><<<g1616, 256, 0, stream>>>(
        arh, arl, nullptr, (long)HD, aph, apl, HD / 32,
        nullptr, nullptr, 0L, orh, orl, oph, opl,
        nullptr, nullptr, nullptr, nullptr, 0);
    arh = orh; arl = orl; aph = oph; apl = opl;
  }

  // phase B: per-chunk local scans -> e_c planes (= KS ping buffer)
  k_scan2<0><<<256, 1024, 0, stream>>>(projS, initial, wt16_h,
                                       nullptr, nullptr, xph, xpl, nullptr, nullptr);

  // phase C: Kogge-Stone inclusive scan over 128 chunk states (7 rounds,
  // barrier-free; one fused launch per round incl. pass-through copies).
  const u16 *xin_h = xph, *xin_l = xpl;
  u16 *xout_h = xqh, *xout_l = xql;
  for (int j = 0; j < 7; ++j) {
    const int d = 1 << j;
    dim3 gks(CCH, 8);
    k_gemm3<4, 4, 4, 0><<<gks, 256, 0, stream>>>(
        xin_h, xin_l, nullptr, (long)HD, wp_pk_h[j], wp_pk_l[j], HD / 32,
        nullptr, nullptr, 0L, xout_h, xout_l,
        nullptr, nullptr, nullptr, nullptr, xin_h, xin_l, d);
    const u16* th = xin_h; const u16* tl = xin_l;
    xin_h = xout_h; xin_l = xout_l;
    xout_h = (u16*)th; xout_l = (u16*)tl;
  }
  // final states in xin_h/xin_l

  // Z-inits: Z_c = S_{c-1} * W^T + projS[:, c*16], c = 1..127 -> bf16 zbuf
  // + per-chunk absmax into zmx.
  dim3 gz(127, 8);
  k_gemm3<2, 4, 4, 0><<<gz, 256, 0, stream>>>(
      xin_h, xin_l, nullptr, (long)HD, wt_pk_h, wt_pk_l, HD / 32,
      projS, nullptr, 0L, nullptr, nullptr, nullptr, nullptr,
      zbuf, zmx, nullptr, nullptr, 0);

  // phase D: emit all hidden states into out1 AND out2 (in-place over projS)
  k_scan2<1><<<256, 1024, 0, stream>>>(projS, initial, wt16_h,
                                       zbuf, zmx, nullptr, nullptr, out1, out2);
}